// Round 7
// baseline (308.662 us; speedup 1.0000x reference)
//
#include <hip/hip_runtime.h>
#include <hip/hip_bf16.h>

// Problem constants
constexpr int BB = 8;
constexpr int LLEN = 2048;
constexpr int HH = 256;
constexpr int EE = 512;          // H * EXP
constexpr int MM = BB * LLEN;    // 16384 rows

typedef short bf16x8 __attribute__((ext_vector_type(8)));
typedef short bf16x4 __attribute__((ext_vector_type(4)));
typedef float f32x4  __attribute__((ext_vector_type(4)));

static __device__ inline unsigned short f2bf(float f) {
    unsigned u = __builtin_bit_cast(unsigned, f);
    unsigned r = (u + 0x7FFFu + ((u >> 16) & 1u)) >> 16;
    return (unsigned short)r;
}
static __device__ inline float bf2f(unsigned short h) {
    return __builtin_bit_cast(float, (unsigned)h << 16);
}

#define GL2LDS(gp, lp) __builtin_amdgcn_global_load_lds( \
    (const __attribute__((address_space(1))) void*)(gp), \
    (__attribute__((address_space(3))) void*)(lp), 16, 0, 0)

// ---------------------------------------------------------------------------
__global__ __launch_bounds__(256) void cast_bf16_kernel(
    const float* __restrict__ in, unsigned short* __restrict__ out)
{
    int b = blockIdx.x;
    int cpx = gridDim.x >> 3;
    int lin = (b & 7) * cpx + (b >> 3);
    int i = (lin * 256 + threadIdx.x) * 4;
    float4 v = *reinterpret_cast<const float4*>(in + i);
    ushort4 o = {f2bf(v.x), f2bf(v.y), f2bf(v.z), f2bf(v.w)};
    *reinterpret_cast<ushort4*>(out + i) = o;
}

__global__ __launch_bounds__(256) void transpose_cast_kernel(
    const float* __restrict__ W, unsigned short* __restrict__ Wt, int K, int N)
{
    int i = blockIdx.x * 256 + threadIdx.x;
    if (i < K * N) {
        int n = i / K, k = i - n * K;
        Wt[i] = f2bf(W[(size_t)k * N + n]);
    }
}

// ---------------------------------------------------------------------------
// K1 ablation variants.  xz = ubf @ wtin^T + b_in; cols<512 -> x, else silu->zs.
// 128x128 tile, K=256, BK=64.  PIPE: double-buffer + counted vmcnt(8).
//                              !PIPE: single buffer, vmcnt(0)+barrier per tile.
// EPVEC: LDS-bounce epilogue (bf16x4 8B stores) vs scalar 2B stores.
// REPS: repeat whole block work (identical writes) to scale dispatch time
// for rocprof visibility.  All variants bitwise-identical output.
// ---------------------------------------------------------------------------
template<int REPS, bool PIPE, bool EPVEC>
__global__ __launch_bounds__(256) void k1_var(
    const unsigned short* __restrict__ A, const unsigned short* __restrict__ Bt,
    const float* __restrict__ bias,
    unsigned short* __restrict__ xb, unsigned short* __restrict__ zsb)
{
    constexpr int NB = PIPE ? 2 : 1;
    constexpr size_t STGB = (size_t)NB * 2 * 128 * 64 * 2;       // A+B staging bytes
    constexpr size_t EPB  = EPVEC ? (size_t)128 * 132 * 2 : 0;   // epilogue bounce
    constexpr size_t LDSZ = STGB > EPB ? STGB : EPB;
    __shared__ __align__(16) char lds_raw[LDSZ];
    unsigned short (*Al)[128 * 64] = (unsigned short(*)[128 * 64])lds_raw;
    unsigned short (*Bl)[128 * 64] =
        (unsigned short(*)[128 * 64])(lds_raw + (size_t)NB * 128 * 64 * 2);
    unsigned short *Ep = (unsigned short*)lds_raw;

    const int tid = threadIdx.x;
    const int lane = tid & 63;
    const int wave = tid >> 6;
    const int wrow = wave >> 1, wcol = wave & 1;
    const int l15 = lane & 15;
    const int lk  = lane >> 4;

    const int cpx = gridDim.x >> 3;
    int lin = blockIdx.x;
    lin = (lin & 7) * cpx + (lin >> 3);
    const int row0 = (lin >> 3) * 128;
    const int col0 = (lin & 7) * 128;
    const bool zside = col0 >= EE;
    unsigned short* Cp = zside ? zsb : xb;
    const int cb = zside ? col0 - EE : col0;

    f32x4 acc[4][4];

    auto stage = [&](int bi, int kt) {
        #pragma unroll
        for (int i = 0; i < 4; ++i) {
            int sid = i * 256 + tid;
            int r = sid >> 3, sl = sid & 7;
            GL2LDS(A + (size_t)(row0 + r) * 256 + kt + ((sl ^ (r & 7)) << 3),
                   &Al[bi][sid * 8]);
        }
        #pragma unroll
        for (int i = 0; i < 4; ++i) {
            int sid = i * 256 + tid;
            int r = sid >> 3, sl = sid & 7;
            GL2LDS(Bt + (size_t)(col0 + r) * 256 + kt + ((sl ^ (r & 7)) << 3),
                   &Bl[bi][sid * 8]);
        }
    };

    auto compute = [&](int bi) {
        bf16x8 af[4][2], bfr[4][2];
        #pragma unroll
        for (int m = 0; m < 4; ++m) {
            const int r = wrow * 64 + m * 16 + l15;
            #pragma unroll
            for (int kk = 0; kk < 2; ++kk) {
                const int sl = (kk * 4 + lk) ^ (r & 7);
                af[m][kk] = *reinterpret_cast<const bf16x8*>(&Al[bi][r * 64 + sl * 8]);
            }
        }
        #pragma unroll
        for (int n = 0; n < 4; ++n) {
            const int r = wcol * 64 + n * 16 + l15;
            #pragma unroll
            for (int kk = 0; kk < 2; ++kk) {
                const int sl = (kk * 4 + lk) ^ (r & 7);
                bfr[n][kk] = *reinterpret_cast<const bf16x8*>(&Bl[bi][r * 64 + sl * 8]);
            }
        }
        #pragma unroll
        for (int kk = 0; kk < 2; ++kk)
            #pragma unroll
            for (int m = 0; m < 4; ++m)
                #pragma unroll
                for (int n = 0; n < 4; ++n)
                    acc[m][n] = __builtin_amdgcn_mfma_f32_16x16x32_bf16(
                        af[m][kk], bfr[n][kk], acc[m][n], 0, 0, 0);
    };

    #pragma unroll 1
    for (int rep = 0; rep < REPS; ++rep) {
        #pragma unroll
        for (int m = 0; m < 4; ++m)
            #pragma unroll
            for (int n = 0; n < 4; ++n)
                acc[m][n] = (f32x4){0.f, 0.f, 0.f, 0.f};

        if (PIPE) {
            stage(0, 0);
            #pragma unroll
            for (int t = 0; t < 4; ++t) {
                const int bi = t & 1;
                if (t < 3) {
                    stage(bi ^ 1, (t + 1) * 64);
                    asm volatile("s_waitcnt vmcnt(8)" ::: "memory");
                } else {
                    asm volatile("s_waitcnt vmcnt(0)" ::: "memory");
                }
                __builtin_amdgcn_sched_barrier(0);
                __builtin_amdgcn_s_barrier();
                compute(bi);
                __builtin_amdgcn_s_barrier();
            }
        } else {
            #pragma unroll
            for (int t = 0; t < 4; ++t) {
                stage(0, t * 64);
                asm volatile("s_waitcnt vmcnt(0)" ::: "memory");
                __builtin_amdgcn_sched_barrier(0);
                __builtin_amdgcn_s_barrier();
                compute(0);
                __builtin_amdgcn_s_barrier();
            }
        }

        if (!EPVEC) {
            // anchor epilogue: scalar 2B stores
            #pragma unroll
            for (int m = 0; m < 4; ++m) {
                #pragma unroll
                for (int n = 0; n < 4; ++n) {
                    const int colloc = wcol * 64 + n * 16 + l15;
                    const float bv = bias[col0 + colloc];
                    #pragma unroll
                    for (int i = 0; i < 4; ++i) {
                        const int row = row0 + wrow * 64 + m * 16 + lk * 4 + i;
                        float v = acc[m][n][i] + bv;
                        if (zside) v = v / (1.f + __expf(-v));
                        Cp[(size_t)row * EE + cb + colloc] = f2bf(v);
                    }
                }
            }
        } else {
            // vectorized epilogue: bf16 via LDS bounce, 8B stores
            #pragma unroll
            for (int m = 0; m < 4; ++m) {
                #pragma unroll
                for (int n = 0; n < 4; ++n) {
                    const int colloc = wcol * 64 + n * 16 + l15;
                    const float bv = bias[col0 + colloc];
                    #pragma unroll
                    for (int i = 0; i < 4; ++i) {
                        const int lrow = wrow * 64 + m * 16 + lk * 4 + i;
                        float v = acc[m][n][i] + bv;
                        if (zside) v = v / (1.f + __expf(-v));
                        Ep[lrow * 132 + colloc] = f2bf(v);
                    }
                }
            }
            __syncthreads();
            const int row = tid >> 1, half = tid & 1;
            unsigned short* gp = Cp + (size_t)(row0 + row) * EE + cb + half * 64;
            const unsigned short* sp = &Ep[row * 132 + half * 64];
            #pragma unroll
            for (int j = 0; j < 16; ++j)
                *reinterpret_cast<bf16x4*>(gp + j * 4) =
                    *reinterpret_cast<const bf16x4*>(sp + j * 4);
        }
        __syncthreads();   // LDS free for next rep
    }
}

// ---------------------------------------------------------------------------
// KB: fused mid + GEMM3 (validated R6, ~<=7us).  Block = 64 rows.
// Phase 1: conv(k=3)+SiLU+Dp+LN+*silu(z) -> g in LDS (bf16, swizzled).
//          (SSM scan is constant over E -> cancelled by LN; W_x/b_x/A_log dead.)
// Phase 2: out = g @ W_out^T + b_out, K=512 single-shot per 64-col B-chunk.
// ---------------------------------------------------------------------------
__global__ __launch_bounds__(256, 1) void kb_mid_gemm3(
    const unsigned short* __restrict__ xb, const unsigned short* __restrict__ zsb,
    const unsigned short* __restrict__ Bt,   // wtout [256][512]
    const float* __restrict__ bias, float* __restrict__ out,
    const float* __restrict__ conv_w, const float* __restrict__ conv_b,
    const float* __restrict__ Dp, const float* __restrict__ ln_g,
    const float* __restrict__ ln_b)
{
    __shared__ unsigned short G[64 * 512];    // 64 KB
    __shared__ unsigned short Bl[64 * 512];   // 64 KB

    const int tid = threadIdx.x;
    const int lane = tid & 63;
    const int wave = tid >> 6;
    const int l15 = lane & 15;
    const int lk  = lane >> 4;

    const int b = blockIdx.x;
    const int lin = (b & 7) * 32 + (b >> 3);
    const int r0 = lin * 64;

    #pragma unroll
    for (int i = 0; i < 16; ++i) {
        int id = i * 256 + tid;
        int r = id >> 6, s = id & 63;
        GL2LDS(Bt + (size_t)r * 512 + ((s ^ (r & 7)) << 3), &Bl[id * 8]);
    }

    const int e0 = lane * 8;
    float cw0[8], cw1[8], cw2[8], cb8[8], dp8[8], lg8[8], lb8[8];
    #pragma unroll
    for (int j = 0; j < 8; ++j) {
        int e = e0 + j;
        cw0[j] = conv_w[e * 3 + 0];
        cw1[j] = conv_w[e * 3 + 1];
        cw2[j] = conv_w[e * 3 + 2];
        cb8[j] = conv_b[e];
        dp8[j] = Dp[e];
        lg8[j] = ln_g[e];
        lb8[j] = ln_b[e];
    }

    for (int it = 0; it < 16; ++it) {
        const int i = wave * 16 + it;
        const int gr = r0 + i;
        const int l = gr & (LLEN - 1);
        const size_t base = (size_t)gr * EE + e0;

        bf16x8 xc = *reinterpret_cast<const bf16x8*>(xb + base);
        bf16x8 xm = {}, xp = {};
        if (l > 0)        xm = *reinterpret_cast<const bf16x8*>(xb + base - EE);
        if (l < LLEN - 1) xp = *reinterpret_cast<const bf16x8*>(xb + base + EE);
        bf16x8 zv = *reinterpret_cast<const bf16x8*>(zsb + base);

        float o[8];
        float s1 = 0.f, s2 = 0.f;
        #pragma unroll
        for (int j = 0; j < 8; ++j) {
            float v = cb8[j]
                    + bf2f((unsigned short)xm[j]) * cw0[j]
                    + bf2f((unsigned short)xc[j]) * cw1[j]
                    + bf2f((unsigned short)xp[j]) * cw2[j];
            float sx = v / (1.f + __expf(-v));
            float oe = dp8[j] * sx;
            o[j] = oe;
            s1 += oe;
            s2 += oe * oe;
        }
        #pragma unroll
        for (int off = 1; off < 64; off <<= 1) {
            s1 += __shfl_xor(s1, off);
            s2 += __shfl_xor(s2, off);
        }
        const float mu  = s1 * (1.f / EE);
        const float var = s2 * (1.f / EE) - mu * mu;
        const float inv = rsqrtf(var + 1e-5f);

        bf16x8 gv;
        #pragma unroll
        for (int j = 0; j < 8; ++j) {
            float gy = ((o[j] - mu) * inv * lg8[j] + lb8[j]) * bf2f((unsigned short)zv[j]);
            gv[j] = (short)f2bf(gy);
        }
        *reinterpret_cast<bf16x8*>(&G[i * 512 + ((lane ^ (i & 7)) << 3)]) = gv;
    }
    __syncthreads();

    const int wrow = wave >> 1, wcol = wave & 1;
    for (int c = 0; c < 4; ++c) {
        f32x4 acc[2][2] = {};
        #pragma unroll
        for (int ks = 0; ks < 16; ++ks) {
            bf16x8 af[2], bfr[2];
            #pragma unroll
            for (int m = 0; m < 2; ++m) {
                const int ra = wrow * 32 + m * 16 + l15;
                const int ph = (ks * 4 + lk) ^ (ra & 7);
                af[m] = *reinterpret_cast<const bf16x8*>(&G[ra * 512 + ph * 8]);
            }
            #pragma unroll
            for (int n = 0; n < 2; ++n) {
                const int rb = wcol * 32 + n * 16 + l15;
                const int ph = (ks * 4 + lk) ^ (rb & 7);
                bfr[n] = *reinterpret_cast<const bf16x8*>(&Bl[rb * 512 + ph * 8]);
            }
            #pragma unroll
            for (int m = 0; m < 2; ++m)
                #pragma unroll
                for (int n = 0; n < 2; ++n)
                    acc[m][n] = __builtin_amdgcn_mfma_f32_16x16x32_bf16(
                        af[m], bfr[n], acc[m][n], 0, 0, 0);
        }
        #pragma unroll
        for (int m = 0; m < 2; ++m) {
            #pragma unroll
            for (int n = 0; n < 2; ++n) {
                int col = c * 64 + wcol * 32 + n * 16 + l15;
                float bv = bias[col];
                #pragma unroll
                for (int i = 0; i < 4; ++i) {
                    int row = r0 + wrow * 32 + m * 16 + lk * 4 + i;
                    out[(size_t)row * HH + col] = acc[m][n][i] + bv;
                }
            }
        }
        if (c < 3) {
            __syncthreads();
            #pragma unroll
            for (int i = 0; i < 16; ++i) {
                int id = i * 256 + tid;
                int r = id >> 6, s = id & 63;
                GL2LDS(Bt + (size_t)((c + 1) * 64 + r) * 512 + ((s ^ (r & 7)) << 3),
                       &Bl[id * 8]);
            }
            __syncthreads();
        }
    }
}

// ---------------------------------------------------------------------------
extern "C" void kernel_launch(void* const* d_in, const int* in_sizes, int n_in,
                              void* d_out, int out_size, void* d_ws, size_t ws_size,
                              hipStream_t stream)
{
    const float* u      = (const float*)d_in[0];
    const float* W_in   = (const float*)d_in[1];
    const float* b_in   = (const float*)d_in[2];
    const float* conv_w = (const float*)d_in[3];
    const float* conv_b = (const float*)d_in[4];
    // d_in[5]=W_x, d_in[6]=b_x, d_in[7]=A_log: dead (scan cancels under LN)
    const float* Dp     = (const float*)d_in[8];
    const float* W_out  = (const float*)d_in[9];
    const float* b_out  = (const float*)d_in[10];
    const float* ln_g   = (const float*)d_in[11];
    const float* ln_b   = (const float*)d_in[12];
    float* out = (float*)d_out;

    char* ws = (char*)d_ws;
    unsigned short* ubf   = (unsigned short*)ws; ws += (size_t)MM * HH * 2;
    unsigned short* wtin  = (unsigned short*)ws; ws += (size_t)1024 * HH * 2;
    unsigned short* wtout = (unsigned short*)ws; ws += (size_t)HH * EE * 2;
    unsigned short* xbuf  = (unsigned short*)ws; ws += (size_t)MM * EE * 2;
    unsigned short* zsbuf = (unsigned short*)ws;

    dim3 blk(256);

    transpose_cast_kernel<<<dim3((1024 * HH + 255) / 256), blk, 0, stream>>>(W_in, wtin, HH, 1024);
    transpose_cast_kernel<<<dim3((HH * EE + 255) / 256), blk, 0, stream>>>(W_out, wtout, EE, HH);
    cast_bf16_kernel<<<dim3(MM * HH / 1024), blk, 0, stream>>>(u, ubf);

    // --- K1 ablation: all variants write identical xbuf/zsbuf ---
    k1_var<1, true,  false><<<dim3(1024), blk, 0, stream>>>(ubf, wtin, b_in, xbuf, zsbuf); // v0 anchor
    k1_var<3, true,  true ><<<dim3(1024), blk, 0, stream>>>(ubf, wtin, b_in, xbuf, zsbuf); // v1 pipe+vec
    k1_var<3, false, false><<<dim3(1024), blk, 0, stream>>>(ubf, wtin, b_in, xbuf, zsbuf); // v2 simple+scalar
    k1_var<6, false, true ><<<dim3(1024), blk, 0, stream>>>(ubf, wtin, b_in, xbuf, zsbuf); // v3 simple+vec

    // KB: fused mid+GEMM3
    kb_mid_gemm3<<<dim3(256), blk, 0, stream>>>(
        xbuf, zsbuf, wtout, b_out, out, conv_w, conv_b, Dp, ln_g, ln_b);
}

// Round 8
// 64.970 us; speedup vs baseline: 4.7509x; 4.7509x over previous
//
#include <hip/hip_runtime.h>
#include <hip/hip_bf16.h>

// Problem constants
constexpr int BB = 8;
constexpr int LLEN = 2048;
constexpr int HH = 256;
constexpr int EE = 512;          // H * EXP
constexpr int MM = BB * LLEN;    // 16384 rows

typedef short bf16x8 __attribute__((ext_vector_type(8)));
typedef float f32x4  __attribute__((ext_vector_type(4)));

static __device__ inline unsigned short f2bf(float f) {
    unsigned u = __builtin_bit_cast(unsigned, f);
    unsigned r = (u + 0x7FFFu + ((u >> 16) & 1u)) >> 16;
    return (unsigned short)r;
}
static __device__ inline float bf2f(unsigned short h) {
    return __builtin_bit_cast(float, (unsigned)h << 16);
}

#define GL2LDS(gp, lp) __builtin_amdgcn_global_load_lds( \
    (const __attribute__((address_space(1))) void*)(gp), \
    (__attribute__((address_space(3))) void*)(lp), 16, 0, 0)

// ---------------------------------------------------------------------------
__global__ __launch_bounds__(256) void cast_bf16_kernel(
    const float* __restrict__ in, unsigned short* __restrict__ out)
{
    int b = blockIdx.x;
    int cpx = gridDim.x >> 3;
    int lin = (b & 7) * cpx + (b >> 3);
    int i = (lin * 256 + threadIdx.x) * 4;
    float4 v = *reinterpret_cast<const float4*>(in + i);
    ushort4 o = {f2bf(v.x), f2bf(v.y), f2bf(v.z), f2bf(v.w)};
    *reinterpret_cast<ushort4*>(out + i) = o;
}

__global__ __launch_bounds__(256) void transpose_cast_kernel(
    const float* __restrict__ W, unsigned short* __restrict__ Wt, int K, int N)
{
    int i = blockIdx.x * 256 + threadIdx.x;
    if (i < K * N) {
        int n = i / K, k = i - n * K;
        Wt[i] = f2bf(W[(size_t)k * N + n]);
    }
}

// ---------------------------------------------------------------------------
// K1 (R7 ablation winner "v2"): xz = ubf @ wtin^T + b_in.
// cols<512 -> x bf16; cols>=512 -> silu -> zs bf16.
// 128x128 tile, K=256, BK=64, SINGLE 32KB LDS buffer -> 5 blocks/CU.
// Per K-tile: 8x global_load_lds (pre-swizzled src), vmcnt(0)+barrier,
// 16 ds_read_b128 + 32 MFMA, barrier.  TLP (not ILP) hides staging latency.
// XCD-chunk blockIdx swizzle; scalar 2B epilogue stores.
// ---------------------------------------------------------------------------
__global__ __launch_bounds__(256) void k1_gemm(
    const unsigned short* __restrict__ A, const unsigned short* __restrict__ Bt,
    const float* __restrict__ bias,
    unsigned short* __restrict__ xb, unsigned short* __restrict__ zsb)
{
    __shared__ unsigned short Al[128 * 64];   // 16 KB
    __shared__ unsigned short Bl[128 * 64];   // 16 KB

    const int tid = threadIdx.x;
    const int lane = tid & 63;
    const int wave = tid >> 6;
    const int wrow = wave >> 1, wcol = wave & 1;
    const int l15 = lane & 15;
    const int lk  = lane >> 4;

    const int cpx = gridDim.x >> 3;
    int lin = blockIdx.x;
    lin = (lin & 7) * cpx + (lin >> 3);
    const int row0 = (lin >> 3) * 128;
    const int col0 = (lin & 7) * 128;
    const bool zside = col0 >= EE;
    unsigned short* Cp = zside ? zsb : xb;
    const int cb = zside ? col0 - EE : col0;

    f32x4 acc[4][4] = {};

    #pragma unroll
    for (int t = 0; t < 4; ++t) {
        const int kt = t * 64;
        // stage A+B k-tile (async DMA, pre-swizzled source, linear LDS dest)
        #pragma unroll
        for (int i = 0; i < 4; ++i) {
            int sid = i * 256 + tid;
            int r = sid >> 3, sl = sid & 7;
            GL2LDS(A + (size_t)(row0 + r) * 256 + kt + ((sl ^ (r & 7)) << 3),
                   &Al[sid * 8]);
        }
        #pragma unroll
        for (int i = 0; i < 4; ++i) {
            int sid = i * 256 + tid;
            int r = sid >> 3, sl = sid & 7;
            GL2LDS(Bt + (size_t)(col0 + r) * 256 + kt + ((sl ^ (r & 7)) << 3),
                   &Bl[sid * 8]);
        }
        asm volatile("s_waitcnt vmcnt(0)" ::: "memory");
        __builtin_amdgcn_sched_barrier(0);
        __builtin_amdgcn_s_barrier();

        bf16x8 af[4][2], bfr[4][2];
        #pragma unroll
        for (int m = 0; m < 4; ++m) {
            const int r = wrow * 64 + m * 16 + l15;
            #pragma unroll
            for (int kk = 0; kk < 2; ++kk) {
                const int sl = (kk * 4 + lk) ^ (r & 7);
                af[m][kk] = *reinterpret_cast<const bf16x8*>(&Al[r * 64 + sl * 8]);
            }
        }
        #pragma unroll
        for (int n = 0; n < 4; ++n) {
            const int r = wcol * 64 + n * 16 + l15;
            #pragma unroll
            for (int kk = 0; kk < 2; ++kk) {
                const int sl = (kk * 4 + lk) ^ (r & 7);
                bfr[n][kk] = *reinterpret_cast<const bf16x8*>(&Bl[r * 64 + sl * 8]);
            }
        }
        #pragma unroll
        for (int kk = 0; kk < 2; ++kk)
            #pragma unroll
            for (int m = 0; m < 4; ++m)
                #pragma unroll
                for (int n = 0; n < 4; ++n)
                    acc[m][n] = __builtin_amdgcn_mfma_f32_16x16x32_bf16(
                        af[m][kk], bfr[n][kk], acc[m][n], 0, 0, 0);

        __builtin_amdgcn_s_barrier();
    }

    // epilogue: C/D layout col = lane&15, row = (lane>>4)*4 + i
    #pragma unroll
    for (int m = 0; m < 4; ++m) {
        #pragma unroll
        for (int n = 0; n < 4; ++n) {
            const int colloc = wcol * 64 + n * 16 + l15;
            const float bv = bias[col0 + colloc];
            #pragma unroll
            for (int i = 0; i < 4; ++i) {
                const int row = row0 + wrow * 64 + m * 16 + lk * 4 + i;
                float v = acc[m][n][i] + bv;
                if (zside) v = v / (1.f + __expf(-v));
                Cp[(size_t)row * EE + cb + colloc] = f2bf(v);
            }
        }
    }
}

// ---------------------------------------------------------------------------
// KB: fused mid + GEMM3 (validated R6/R7).  Block = 64 rows.
// Phase 1: conv(k=3)+SiLU+Dp+LN+*silu(z) -> g in LDS (bf16, swizzled).
//          (SSM scan is constant over E -> cancelled by LN; W_x/b_x/A_log dead.)
// Phase 2: out = g @ W_out^T + b_out, K=512 single-shot per 64-col B-chunk.
// ---------------------------------------------------------------------------
__global__ __launch_bounds__(256, 1) void kb_mid_gemm3(
    const unsigned short* __restrict__ xb, const unsigned short* __restrict__ zsb,
    const unsigned short* __restrict__ Bt,   // wtout [256][512]
    const float* __restrict__ bias, float* __restrict__ out,
    const float* __restrict__ conv_w, const float* __restrict__ conv_b,
    const float* __restrict__ Dp, const float* __restrict__ ln_g,
    const float* __restrict__ ln_b)
{
    __shared__ unsigned short G[64 * 512];    // 64 KB
    __shared__ unsigned short Bl[64 * 512];   // 64 KB

    const int tid = threadIdx.x;
    const int lane = tid & 63;
    const int wave = tid >> 6;
    const int l15 = lane & 15;
    const int lk  = lane >> 4;

    const int b = blockIdx.x;
    const int lin = (b & 7) * 32 + (b >> 3);
    const int r0 = lin * 64;

    #pragma unroll
    for (int i = 0; i < 16; ++i) {
        int id = i * 256 + tid;
        int r = id >> 6, s = id & 63;
        GL2LDS(Bt + (size_t)r * 512 + ((s ^ (r & 7)) << 3), &Bl[id * 8]);
    }

    const int e0 = lane * 8;
    float cw0[8], cw1[8], cw2[8], cb8[8], dp8[8], lg8[8], lb8[8];
    #pragma unroll
    for (int j = 0; j < 8; ++j) {
        int e = e0 + j;
        cw0[j] = conv_w[e * 3 + 0];
        cw1[j] = conv_w[e * 3 + 1];
        cw2[j] = conv_w[e * 3 + 2];
        cb8[j] = conv_b[e];
        dp8[j] = Dp[e];
        lg8[j] = ln_g[e];
        lb8[j] = ln_b[e];
    }

    for (int it = 0; it < 16; ++it) {
        const int i = wave * 16 + it;
        const int gr = r0 + i;
        const int l = gr & (LLEN - 1);
        const size_t base = (size_t)gr * EE + e0;

        bf16x8 xc = *reinterpret_cast<const bf16x8*>(xb + base);
        bf16x8 xm = {}, xp = {};
        if (l > 0)        xm = *reinterpret_cast<const bf16x8*>(xb + base - EE);
        if (l < LLEN - 1) xp = *reinterpret_cast<const bf16x8*>(xb + base + EE);
        bf16x8 zv = *reinterpret_cast<const bf16x8*>(zsb + base);

        float o[8];
        float s1 = 0.f, s2 = 0.f;
        #pragma unroll
        for (int j = 0; j < 8; ++j) {
            float v = cb8[j]
                    + bf2f((unsigned short)xm[j]) * cw0[j]
                    + bf2f((unsigned short)xc[j]) * cw1[j]
                    + bf2f((unsigned short)xp[j]) * cw2[j];
            float sx = v / (1.f + __expf(-v));
            float oe = dp8[j] * sx;
            o[j] = oe;
            s1 += oe;
            s2 += oe * oe;
        }
        #pragma unroll
        for (int off = 1; off < 64; off <<= 1) {
            s1 += __shfl_xor(s1, off);
            s2 += __shfl_xor(s2, off);
        }
        const float mu  = s1 * (1.f / EE);
        const float var = s2 * (1.f / EE) - mu * mu;
        const float inv = rsqrtf(var + 1e-5f);

        bf16x8 gv;
        #pragma unroll
        for (int j = 0; j < 8; ++j) {
            float gy = ((o[j] - mu) * inv * lg8[j] + lb8[j]) * bf2f((unsigned short)zv[j]);
            gv[j] = (short)f2bf(gy);
        }
        *reinterpret_cast<bf16x8*>(&G[i * 512 + ((lane ^ (i & 7)) << 3)]) = gv;
    }
    __syncthreads();

    const int wrow = wave >> 1, wcol = wave & 1;
    for (int c = 0; c < 4; ++c) {
        f32x4 acc[2][2] = {};
        #pragma unroll
        for (int ks = 0; ks < 16; ++ks) {
            bf16x8 af[2], bfr[2];
            #pragma unroll
            for (int m = 0; m < 2; ++m) {
                const int ra = wrow * 32 + m * 16 + l15;
                const int ph = (ks * 4 + lk) ^ (ra & 7);
                af[m] = *reinterpret_cast<const bf16x8*>(&G[ra * 512 + ph * 8]);
            }
            #pragma unroll
            for (int n = 0; n < 2; ++n) {
                const int rb = wcol * 32 + n * 16 + l15;
                const int ph = (ks * 4 + lk) ^ (rb & 7);
                bfr[n] = *reinterpret_cast<const bf16x8*>(&Bl[rb * 512 + ph * 8]);
            }
            #pragma unroll
            for (int m = 0; m < 2; ++m)
                #pragma unroll
                for (int n = 0; n < 2; ++n)
                    acc[m][n] = __builtin_amdgcn_mfma_f32_16x16x32_bf16(
                        af[m], bfr[n], acc[m][n], 0, 0, 0);
        }
        #pragma unroll
        for (int m = 0; m < 2; ++m) {
            #pragma unroll
            for (int n = 0; n < 2; ++n) {
                int col = c * 64 + wcol * 32 + n * 16 + l15;
                float bv = bias[col];
                #pragma unroll
                for (int i = 0; i < 4; ++i) {
                    int row = r0 + wrow * 32 + m * 16 + lk * 4 + i;
                    out[(size_t)row * HH + col] = acc[m][n][i] + bv;
                }
            }
        }
        if (c < 3) {
            __syncthreads();
            #pragma unroll
            for (int i = 0; i < 16; ++i) {
                int id = i * 256 + tid;
                int r = id >> 6, s = id & 63;
                GL2LDS(Bt + (size_t)((c + 1) * 64 + r) * 512 + ((s ^ (r & 7)) << 3),
                       &Bl[id * 8]);
            }
            __syncthreads();
        }
    }
}

// ---------------------------------------------------------------------------
extern "C" void kernel_launch(void* const* d_in, const int* in_sizes, int n_in,
                              void* d_out, int out_size, void* d_ws, size_t ws_size,
                              hipStream_t stream)
{
    const float* u      = (const float*)d_in[0];
    const float* W_in   = (const float*)d_in[1];
    const float* b_in   = (const float*)d_in[2];
    const float* conv_w = (const float*)d_in[3];
    const float* conv_b = (const float*)d_in[4];
    // d_in[5]=W_x, d_in[6]=b_x, d_in[7]=A_log: dead (scan cancels under LN)
    const float* Dp     = (const float*)d_in[8];
    const float* W_out  = (const float*)d_in[9];
    const float* b_out  = (const float*)d_in[10];
    const float* ln_g   = (const float*)d_in[11];
    const float* ln_b   = (const float*)d_in[12];
    float* out = (float*)d_out;

    char* ws = (char*)d_ws;
    unsigned short* ubf   = (unsigned short*)ws; ws += (size_t)MM * HH * 2;
    unsigned short* wtin  = (unsigned short*)ws; ws += (size_t)1024 * HH * 2;
    unsigned short* wtout = (unsigned short*)ws; ws += (size_t)HH * EE * 2;
    unsigned short* xbuf  = (unsigned short*)ws; ws += (size_t)MM * EE * 2;
    unsigned short* zsbuf = (unsigned short*)ws;

    dim3 blk(256);

    transpose_cast_kernel<<<dim3((1024 * HH + 255) / 256), blk, 0, stream>>>(W_in, wtin, HH, 1024);
    transpose_cast_kernel<<<dim3((HH * EE + 255) / 256), blk, 0, stream>>>(W_out, wtout, EE, HH);
    cast_bf16_kernel<<<dim3(MM * HH / 1024), blk, 0, stream>>>(u, ubf);

    // K1: high-occupancy simple loop (R7 winner)
    k1_gemm<<<dim3(1024), blk, 0, stream>>>(ubf, wtin, b_in, xbuf, zsbuf);

    // KB: fused mid+GEMM3
    kb_mid_gemm3<<<dim3(256), blk, 0, stream>>>(
        xbuf, zsbuf, wtout, b_out, out, conv_w, conv_b, Dp, ln_g, ln_b);
}